// Round 1
// baseline (944.868 us; speedup 1.0000x reference)
//
#include <hip/hip_runtime.h>
#include <math.h>

// Problem constants
#define BB 16
#define CC 256
#define HH 128
#define WW 128
#define HWSZ 16384        // H*W
#define NF 8
#define NGROUP 8
#define CPG 32            // channels per group
#define EPSV 1e-5f

// ---------------------------------------------------------------------------
// K0: transpose proj_w [o][c] -> wT [c][o]  (one-off, 256 KB, L2-resident)
// ---------------------------------------------------------------------------
__global__ __launch_bounds__(256) void transpose_w_kernel(
    const float* __restrict__ pw, float* __restrict__ wT) {
  int c = blockIdx.x;       // 0..255
  int o = threadIdx.x;      // 0..255
  wT[(size_t)c * 256 + o] = pw[(size_t)o * 256 + c];
}

// ---------------------------------------------------------------------------
// K1: pooled[b,c] = mean over HW.  One block per (b,c) plane.
// ---------------------------------------------------------------------------
__global__ __launch_bounds__(256) void pool_kernel(
    const float* __restrict__ x, float* __restrict__ pooled) {
  int plane = blockIdx.x;   // b*256 + c
  const float4* xp = (const float4*)(x + (size_t)plane * HWSZ);
  int tid = threadIdx.x;
  float s = 0.f;
#pragma unroll
  for (int i = 0; i < 16; ++i) {
    float4 v = xp[tid + i * 256];
    s += v.x + v.y + v.z + v.w;
  }
#pragma unroll
  for (int off = 32; off > 0; off >>= 1) s += __shfl_down(s, off, 64);
  __shared__ float ls[4];
  if ((tid & 63) == 0) ls[tid >> 6] = s;
  __syncthreads();
  if (tid == 0) pooled[plane] = (ls[0] + ls[1] + ls[2] + ls[3]) * (1.0f / 16384.0f);
}

// ---------------------------------------------------------------------------
// K2: selector: logits = pooled @ sel_w.T + sel_b ; softmax ; mix filter bank.
//     Also zeroes the GN stats accumulators (re-zeroed every call).
//     Single block, 256 threads.
// ---------------------------------------------------------------------------
__global__ __launch_bounds__(256) void selector_kernel(
    const float* __restrict__ pooled, const float* __restrict__ sel_w,
    const float* __restrict__ sel_b, const float* __restrict__ fbank,
    float* __restrict__ combined, float* __restrict__ stats) {
  int tid = threadIdx.x;
  stats[tid] = 0.f;  // 256 slots: [0..127] sum, [128..255] sumsq
  __shared__ float lg[BB][NF];
  __shared__ float wsm[BB][NF];
  if (tid < BB * NF) {
    int b = tid >> 3, n = tid & 7;
    const float* p = pooled + b * CC;
    const float* w = sel_w + n * CC;
    float d = sel_b[n];
    for (int c = 0; c < CC; c += 4) {
      d += p[c] * w[c] + p[c + 1] * w[c + 1] + p[c + 2] * w[c + 2] + p[c + 3] * w[c + 3];
    }
    lg[b][n] = d;
  }
  __syncthreads();
  if (tid < BB) {
    int b = tid;
    float m = lg[b][0];
#pragma unroll
    for (int n = 1; n < NF; ++n) m = fmaxf(m, lg[b][n]);
    float e[NF];
    float s = 0.f;
#pragma unroll
    for (int n = 0; n < NF; ++n) { e[n] = expf(lg[b][n] - m); s += e[n]; }
    float inv = 1.0f / s;
#pragma unroll
    for (int n = 0; n < NF; ++n) wsm[b][n] = e[n] * inv;
  }
  __syncthreads();
  // combined[b][j] = sum_n wsm[b][n] * fbank[n][j],  j in 0..48, padded stride 64
  for (int i = tid; i < BB * 49; i += 256) {
    int b = i / 49, j = i % 49;
    float acc = 0.f;
#pragma unroll
    for (int n = 0; n < NF; ++n) acc += wsm[b][n] * fbank[n * 49 + j];
    combined[b * 64 + j] = acc;
  }
}

// ---------------------------------------------------------------------------
// K3: depthwise 7x7 conv, per-sample filter (49 taps in registers).
//     Block = one (b,c) plane x 32-row tile. LDS holds 38 rows x 136 cols
//     (col-shifted by +4 for aligned float4 reads, zero-padded halo).
//     Thread computes 4 rows x 4 cols.
// ---------------------------------------------------------------------------
#define TR 32
__global__ __launch_bounds__(256) void dwconv_kernel(
    const float* __restrict__ x, const float* __restrict__ combined,
    float* __restrict__ filtered) {
  int plane = blockIdx.x;          // b*256 + c
  int rt = blockIdx.y;             // 0..3
  int b = plane >> 8;
  int r0 = rt * TR;
  int tid = threadIdx.x;

  __shared__ float xs[TR + 6][136];

  // filter -> registers (uniform per block)
  float kf[49];
  {
    const float* cb = combined + b * 64;
#pragma unroll
    for (int i = 0; i < 49; ++i) kf[i] = cb[i];
  }

  const size_t pbase = (size_t)plane * HWSZ;
  // stage rows r0-3 .. r0+TR+2, cols -4..131 (pad -> 0)
  for (int idx = tid; idx < (TR + 6) * 34; idx += 256) {
    int row = idx / 34;            // 0..37
    int seg = idx % 34;            // 4-float segment
    int r = r0 - 3 + row;
    int c = seg * 4 - 4;           // -4 .. 128
    float4 v = make_float4(0.f, 0.f, 0.f, 0.f);
    if (r >= 0 && r < HH && c >= 0 && c < WW) {
      v = *(const float4*)(x + pbase + (size_t)r * WW + c);
    }
    *(float4*)&xs[row][seg * 4] = v;
  }
  __syncthreads();

  int cg = tid & 31;               // col group: cols 4cg..4cg+3
  int rg = tid >> 5;               // row group: rows 4rg..4rg+3 (rel to r0)
  float acc[4][4] = {};

#pragma unroll
  for (int ri = 0; ri < 10; ++ri) {          // input rows 4rg-3 .. 4rg+6
    int lrow = 4 * rg + ri;                  // LDS row index
    float xr[12];
#pragma unroll
    for (int s = 0; s < 3; ++s)
      *(float4*)&xr[4 * s] = *(const float4*)&xs[lrow][cg * 4 + 4 * s];
    // xr[j] = x col (4cg - 4 + j); tap (orr,oc,dx) uses xr[oc+dx+1], dy = ri-orr
#pragma unroll
    for (int orr = 0; orr < 4; ++orr) {
      int dy = ri - orr;
      if (dy < 0 || dy > 6) continue;        // compile-time pruned
#pragma unroll
      for (int oc = 0; oc < 4; ++oc) {
#pragma unroll
        for (int dx = 0; dx < 7; ++dx) {
          acc[orr][oc] += xr[oc + dx + 1] * kf[dy * 7 + dx];
        }
      }
    }
  }

#pragma unroll
  for (int orr = 0; orr < 4; ++orr) {
    float4 sv = make_float4(acc[orr][0], acc[orr][1], acc[orr][2], acc[orr][3]);
    *(float4*)(filtered + pbase + (size_t)(r0 + 4 * rg + orr) * WW + 4 * cg) = sv;
  }
}

// ---------------------------------------------------------------------------
// K4: 1x1 conv as fp32 GEMM: y[b,o,p] = sum_c wT[c][o] * filtered[b,c,p] + pb[o]
//     Block: one sample x 128-pixel tile; M=256 (all out ch), thread = 16x8 tile.
//     Epilogue: write y to d_out, accumulate GN partial sums via atomics.
// ---------------------------------------------------------------------------
__global__ __launch_bounds__(256, 2) void gemm_kernel(
    const float* __restrict__ filtered, const float* __restrict__ wT,
    const float* __restrict__ proj_b, float* __restrict__ y,
    float* __restrict__ stats) {
  int bs = blockIdx.x >> 7;        // sample
  int pt = blockIdx.x & 127;       // pixel tile
  int p0 = pt * 128;
  int tid = threadIdx.x;
  int tm = tid >> 4;               // 0..15 -> out ch o = tm*16..tm*16+15
  int tn = tid & 15;               // 0..15 -> pixels p0+tn*8..+7

  __shared__ float As[16][256];    // [kk][o]
  __shared__ float Bs[16][128];    // [kk][p]

  float acc[16][8] = {};
  const size_t fbase = (size_t)bs * CC * HWSZ + p0;

  for (int c0 = 0; c0 < CC; c0 += 16) {
#pragma unroll
    for (int kk = 0; kk < 16; ++kk) As[kk][tid] = wT[(size_t)(c0 + kk) * 256 + tid];
#pragma unroll
    for (int l = 0; l < 8; ++l) {
      int idx = tid + l * 256;
      int kk = idx >> 7, j = idx & 127;
      Bs[kk][j] = filtered[fbase + (size_t)(c0 + kk) * HWSZ + j];
    }
    __syncthreads();
    for (int kk = 0; kk < 16; ++kk) {
      float a[16], bb[8];
#pragma unroll
      for (int s = 0; s < 4; ++s) *(float4*)&a[4 * s] = *(const float4*)&As[kk][tm * 16 + 4 * s];
#pragma unroll
      for (int s = 0; s < 2; ++s) *(float4*)&bb[4 * s] = *(const float4*)&Bs[kk][tn * 8 + 4 * s];
#pragma unroll
      for (int i = 0; i < 16; ++i) {
#pragma unroll
        for (int j = 0; j < 8; ++j) acc[i][j] += a[i] * bb[j];
      }
    }
    __syncthreads();
  }

  // epilogue: bias, store y, GN partial sums
  float psum = 0.f, psq = 0.f;
  const size_t ybase = (size_t)bs * CC * HWSZ + p0;
#pragma unroll
  for (int i = 0; i < 16; ++i) {
    int o = tm * 16 + i;
    float pb = proj_b[o];
    float v[8];
#pragma unroll
    for (int j = 0; j < 8; ++j) {
      v[j] = acc[i][j] + pb;
      psum += v[j];
      psq += v[j] * v[j];
    }
    float* yp = y + ybase + (size_t)o * HWSZ + tn * 8;
    *(float4*)yp = make_float4(v[0], v[1], v[2], v[3]);
    *(float4*)(yp + 4) = make_float4(v[4], v[5], v[6], v[7]);
  }
  // lanes 0..31 of each wave share one GN group; reduce width-32
#pragma unroll
  for (int off = 16; off > 0; off >>= 1) {
    psum += __shfl_down(psum, off, 32);
    psq += __shfl_down(psq, off, 32);
  }
  if ((tid & 31) == 0) {
    int g = tid >> 5;              // == tm>>1, group 0..7
    atomicAdd(&stats[bs * 8 + g], psum);
    atomicAdd(&stats[128 + bs * 8 + g], psq);
  }
}

// ---------------------------------------------------------------------------
// K5: GroupNorm affine + exact GELU + residual. In-place on d_out (y -> out).
//     One block per (b,c) plane.
// ---------------------------------------------------------------------------
__global__ __launch_bounds__(256) void out_kernel(
    const float* __restrict__ x, const float* __restrict__ stats,
    const float* __restrict__ gamma, const float* __restrict__ beta,
    float* __restrict__ out) {
  int plane = blockIdx.x;
  int b = plane >> 8, c = plane & 255, g = c >> 5;
  const float inv_n = 1.0f / ((float)CPG * (float)HWSZ);
  float mean = stats[b * 8 + g] * inv_n;
  float var = stats[128 + b * 8 + g] * inv_n - mean * mean;
  float rstd = rsqrtf(var + EPSV);
  float scale = gamma[c] * rstd;
  float shift = beta[c] - mean * scale;

  const size_t base = (size_t)plane * HWSZ;
  for (int i = threadIdx.x; i < HWSZ / 4; i += 256) {
    float4 v = *(const float4*)(out + base + 4 * (size_t)i);
    float4 xv = *(const float4*)(x + base + 4 * (size_t)i);
    float r[4] = {v.x, v.y, v.z, v.w};
    float xr[4] = {xv.x, xv.y, xv.z, xv.w};
#pragma unroll
    for (int k = 0; k < 4; ++k) {
      float t = r[k] * scale + shift;
      float ge = 0.5f * t * (1.0f + erff(t * 0.70710678118654752f));
      r[k] = ge + xr[k];
    }
    *(float4*)(out + base + 4 * (size_t)i) = make_float4(r[0], r[1], r[2], r[3]);
  }
}

// ---------------------------------------------------------------------------
extern "C" void kernel_launch(void* const* d_in, const int* in_sizes, int n_in,
                              void* d_out, int out_size, void* d_ws, size_t ws_size,
                              hipStream_t stream) {
  const float* x      = (const float*)d_in[0];
  const float* fbank  = (const float*)d_in[1];   // [NF,1,7,7]
  const float* sel_w  = (const float*)d_in[2];   // [NF,C]
  const float* sel_b  = (const float*)d_in[3];   // [NF]
  const float* proj_w = (const float*)d_in[4];   // [C,C,1,1]
  const float* proj_b = (const float*)d_in[5];   // [C]
  const float* gamma  = (const float*)d_in[6];   // [C]
  const float* beta   = (const float*)d_in[7];   // [C]
  float* out = (float*)d_out;
  float* ws = (float*)d_ws;

  // ws layout (floats): filtered[B*C*HW] | wT[256*256] | pooled[4096] | combined[16*64] | stats[256]
  float* filtered = ws;
  float* wT       = ws + (size_t)BB * CC * HWSZ;
  float* pooled   = wT + 256 * 256;
  float* combined = pooled + BB * CC;
  float* stats    = combined + BB * 64;

  hipLaunchKernelGGL(transpose_w_kernel, dim3(256), dim3(256), 0, stream, proj_w, wT);
  hipLaunchKernelGGL(pool_kernel, dim3(BB * CC), dim3(256), 0, stream, x, pooled);
  hipLaunchKernelGGL(selector_kernel, dim3(1), dim3(256), 0, stream,
                     pooled, sel_w, sel_b, fbank, combined, stats);
  hipLaunchKernelGGL(dwconv_kernel, dim3(BB * CC, HH / TR), dim3(256), 0, stream,
                     x, combined, filtered);
  hipLaunchKernelGGL(gemm_kernel, dim3(BB * (HWSZ / 128)), dim3(256), 0, stream,
                     filtered, wT, proj_b, out, stats);
  hipLaunchKernelGGL(out_kernel, dim3(BB * CC), dim3(256), 0, stream,
                     x, stats, gamma, beta, out);
}

// Round 2
// 599.191 us; speedup vs baseline: 1.5769x; 1.5769x over previous
//
#include <hip/hip_runtime.h>
#include <math.h>

// Problem constants
#define BB 16
#define CC 256
#define HH 128
#define WW 128
#define HWSZ 16384        // H*W
#define NF 8
#define EPSV 1e-5f

typedef __attribute__((ext_vector_type(8))) short short8;   // 8 bf16 = 4 VGPRs
typedef __attribute__((ext_vector_type(4))) float f32x4;

static __device__ __forceinline__ unsigned short f2bf(float f) {
  unsigned int u = __float_as_uint(f);
  u += 0x7fffu + ((u >> 16) & 1u);       // round-to-nearest-even
  return (unsigned short)(u >> 16);
}

// ---------------------------------------------------------------------------
// K0: pack proj_w [o][c] fp32 -> bf16 in MFMA A-fragment order:
//     ap[((MB*8+kb)*64+lane)*8+e] = w[MB*16+(lane&15)][kb*32+(lane>>4)*8+e]
// ---------------------------------------------------------------------------
__global__ __launch_bounds__(256) void pack_a_kernel(
    const float* __restrict__ pw, unsigned short* __restrict__ ap) {
  int idx = blockIdx.x * 256 + threadIdx.x;     // 0..65535
  int e = idx & 7;
  int lane = (idx >> 3) & 63;
  int kb = (idx >> 9) & 7;
  int mb = idx >> 12;
  int o = mb * 16 + (lane & 15);
  int c = kb * 32 + (lane >> 4) * 8 + e;
  ap[idx] = f2bf(pw[o * 256 + c]);
}

// ---------------------------------------------------------------------------
// K1: pooled[b,c] = mean over HW.  One block per (b,c) plane.
// ---------------------------------------------------------------------------
__global__ __launch_bounds__(256) void pool_kernel(
    const float* __restrict__ x, float* __restrict__ pooled) {
  int plane = blockIdx.x;
  const float4* xp = (const float4*)(x + (size_t)plane * HWSZ);
  int tid = threadIdx.x;
  float s = 0.f;
#pragma unroll
  for (int i = 0; i < 16; ++i) {
    float4 v = xp[tid + i * 256];
    s += v.x + v.y + v.z + v.w;
  }
#pragma unroll
  for (int off = 32; off > 0; off >>= 1) s += __shfl_down(s, off, 64);
  __shared__ float ls[4];
  if ((tid & 63) == 0) ls[tid >> 6] = s;
  __syncthreads();
  if (tid == 0) pooled[plane] = (ls[0] + ls[1] + ls[2] + ls[3]) * (1.0f / 16384.0f);
}

// ---------------------------------------------------------------------------
// K2: selector: GAP -> linear -> softmax -> mix filter bank; zero GN stats.
// ---------------------------------------------------------------------------
__global__ __launch_bounds__(256) void selector_kernel(
    const float* __restrict__ pooled, const float* __restrict__ sel_w,
    const float* __restrict__ sel_b, const float* __restrict__ fbank,
    float* __restrict__ combined, float* __restrict__ stats) {
  int tid = threadIdx.x;
  stats[tid] = 0.f;  // 256 slots: [0..127] sum, [128..255] sumsq
  __shared__ float lg[BB][NF];
  __shared__ float wsm[BB][NF];
  if (tid < BB * NF) {
    int b = tid >> 3, n = tid & 7;
    const float* p = pooled + b * CC;
    const float* w = sel_w + n * CC;
    float d = sel_b[n];
    for (int c = 0; c < CC; c += 4) {
      d += p[c] * w[c] + p[c + 1] * w[c + 1] + p[c + 2] * w[c + 2] + p[c + 3] * w[c + 3];
    }
    lg[b][n] = d;
  }
  __syncthreads();
  if (tid < BB) {
    int b = tid;
    float m = lg[b][0];
#pragma unroll
    for (int n = 1; n < NF; ++n) m = fmaxf(m, lg[b][n]);
    float e[NF];
    float s = 0.f;
#pragma unroll
    for (int n = 0; n < NF; ++n) { e[n] = expf(lg[b][n] - m); s += e[n]; }
    float inv = 1.0f / s;
#pragma unroll
    for (int n = 0; n < NF; ++n) wsm[b][n] = e[n] * inv;
  }
  __syncthreads();
  for (int i = tid; i < BB * 49; i += 256) {
    int b = i / 49, j = i % 49;
    float acc = 0.f;
#pragma unroll
    for (int n = 0; n < NF; ++n) acc += wsm[b][n] * fbank[n * 49 + j];
    combined[b * 64 + j] = acc;
  }
}

// ---------------------------------------------------------------------------
// K3: depthwise 7x7 conv, per-sample filter; fp32 compute, bf16 output.
// ---------------------------------------------------------------------------
#define TR 32
__global__ __launch_bounds__(256) void dwconv_kernel(
    const float* __restrict__ x, const float* __restrict__ combined,
    unsigned short* __restrict__ fbp) {
  int plane = blockIdx.x;          // b*256 + c
  int rt = blockIdx.y;             // 0..3
  int b = plane >> 8;
  int r0 = rt * TR;
  int tid = threadIdx.x;

  __shared__ float xs[TR + 6][136];

  float kf[49];
  {
    const float* cb = combined + b * 64;
#pragma unroll
    for (int i = 0; i < 49; ++i) kf[i] = cb[i];
  }

  const size_t pbase = (size_t)plane * HWSZ;
  for (int idx = tid; idx < (TR + 6) * 34; idx += 256) {
    int row = idx / 34;
    int seg = idx % 34;
    int r = r0 - 3 + row;
    int c = seg * 4 - 4;
    float4 v = make_float4(0.f, 0.f, 0.f, 0.f);
    if (r >= 0 && r < HH && c >= 0 && c < WW) {
      v = *(const float4*)(x + pbase + (size_t)r * WW + c);
    }
    *(float4*)&xs[row][seg * 4] = v;
  }
  __syncthreads();

  int cg = tid & 31;
  int rg = tid >> 5;
  float acc[4][4] = {};

#pragma unroll
  for (int ri = 0; ri < 10; ++ri) {
    int lrow = 4 * rg + ri;
    float xr[12];
#pragma unroll
    for (int s = 0; s < 3; ++s)
      *(float4*)&xr[4 * s] = *(const float4*)&xs[lrow][cg * 4 + 4 * s];
#pragma unroll
    for (int orr = 0; orr < 4; ++orr) {
      int dy = ri - orr;
      if (dy < 0 || dy > 6) continue;
#pragma unroll
      for (int oc = 0; oc < 4; ++oc) {
#pragma unroll
        for (int dx = 0; dx < 7; ++dx) {
          acc[orr][oc] += xr[oc + dx + 1] * kf[dy * 7 + dx];
        }
      }
    }
  }

#pragma unroll
  for (int orr = 0; orr < 4; ++orr) {
    ushort4 sv;
    sv.x = f2bf(acc[orr][0]);
    sv.y = f2bf(acc[orr][1]);
    sv.z = f2bf(acc[orr][2]);
    sv.w = f2bf(acc[orr][3]);
    *(ushort4*)(fbp + pbase + (size_t)(r0 + 4 * rg + orr) * WW + 4 * cg) = sv;
  }
}

// ---------------------------------------------------------------------------
// K4: 1x1 conv as bf16 MFMA GEMM: y[b,o,p] = sum_c W[o][c]*F[b][c][p] + pb[o]
//     128x128 tile/block, 4 waves (2x2 of 64x64), 16x16x32 bf16 MFMA, K=256.
//     B staged to LDS transposed [p][c] with XOR slot swizzle, double-buffered.
//     Epilogue: y store + GN group partial sums (atomics).
// ---------------------------------------------------------------------------
#define SWZ(p) ((((p) >> 1) ^ ((p) >> 4)) & 3)

__global__ __launch_bounds__(256, 2) void gemm_kernel(
    const unsigned short* __restrict__ fb, const unsigned short* __restrict__ ap,
    const float* __restrict__ proj_b, float* __restrict__ y,
    float* __restrict__ stats) {
  int bid = blockIdx.x;
  int bs = bid >> 8;
  int ot = (bid >> 7) & 1;
  int pt = bid & 127;
  int p0 = pt * 128, o0 = ot * 128;
  int tid = threadIdx.x;
  int lane = tid & 63;
  int wave = tid >> 6;
  int wm = wave >> 1, wn = wave & 1;

  __shared__ unsigned short Bs[2][128][32];

  // staging mapping: thread -> 2 consecutive c-rows (2*cpair,2*cpair+1), 8 p
  int cpair = tid >> 4;            // 0..15
  int pseg = tid & 15;             // 0..15 -> p = pseg*8..+7
  const size_t fbase = (size_t)bs * CC * HWSZ + p0;
  const unsigned short* srcA = fb + fbase + (size_t)(2 * cpair) * HWSZ + pseg * 8;

  // A fragment base for this wave/lane
  const unsigned short* apl = ap + (size_t)(ot * 8 + wm * 4) * 4096 + lane * 8;

  f32x4 acc[4][4];
#pragma unroll
  for (int mb = 0; mb < 4; ++mb)
#pragma unroll
    for (int nb = 0; nb < 4; ++nb) acc[mb][nb] = (f32x4){0.f, 0.f, 0.f, 0.f};

  // ---- prologue: tile 0 -> LDS buf 0; A frags for kb=0
  uint4 va = *(const uint4*)(srcA);
  uint4 vb = *(const uint4*)(srcA + HWSZ);
  {
    unsigned int wa[4] = {va.x, va.y, va.z, va.w};
    unsigned int wb[4] = {vb.x, vb.y, vb.z, vb.w};
#pragma unroll
    for (int j = 0; j < 8; ++j) {
      int p = pseg * 8 + j;
      int cc = (2 * cpair) ^ (SWZ(p) << 3);
      unsigned int lo = (wa[j >> 1] >> ((j & 1) * 16)) & 0xffffu;
      unsigned int hi = (wb[j >> 1] >> ((j & 1) * 16)) & 0xffffu;
      *(unsigned int*)&Bs[0][p][cc] = lo | (hi << 16);
    }
  }
  short8 af[4];
#pragma unroll
  for (int mb = 0; mb < 4; ++mb)
    af[mb] = *(const short8*)(apl + mb * 4096);
  __syncthreads();

  for (int kb = 0; kb < 8; ++kb) {
    int cur = kb & 1;
    uint4 na, nb4;
    short8 afn[4];
    if (kb < 7) {
      const unsigned short* s = srcA + (size_t)(kb + 1) * 32 * HWSZ;
      na = *(const uint4*)(s);
      nb4 = *(const uint4*)(s + HWSZ);
#pragma unroll
      for (int mb = 0; mb < 4; ++mb)
        afn[mb] = *(const short8*)(apl + mb * 4096 + (kb + 1) * 512);
    }
    // B fragments from LDS
    short8 bfr[4];
#pragma unroll
    for (int nb = 0; nb < 4; ++nb) {
      int pp = wn * 64 + nb * 16 + (lane & 15);
      int cc0 = ((lane >> 4) * 8) ^ (SWZ(pp) << 3);
      bfr[nb] = *(const short8*)&Bs[cur][pp][cc0];
    }
#pragma unroll
    for (int mb = 0; mb < 4; ++mb)
#pragma unroll
      for (int nb = 0; nb < 4; ++nb)
        acc[mb][nb] = __builtin_amdgcn_mfma_f32_16x16x32_bf16(af[mb], bfr[nb], acc[mb][nb], 0, 0, 0);
    if (kb < 7) {
#pragma unroll
      for (int mb = 0; mb < 4; ++mb) af[mb] = afn[mb];
      unsigned int wa[4] = {na.x, na.y, na.z, na.w};
      unsigned int wb[4] = {nb4.x, nb4.y, nb4.z, nb4.w};
#pragma unroll
      for (int j = 0; j < 8; ++j) {
        int p = pseg * 8 + j;
        int cc = (2 * cpair) ^ (SWZ(p) << 3);
        unsigned int lo = (wa[j >> 1] >> ((j & 1) * 16)) & 0xffffu;
        unsigned int hi = (wb[j >> 1] >> ((j & 1) * 16)) & 0xffffu;
        *(unsigned int*)&Bs[cur ^ 1][p][cc] = lo | (hi << 16);
      }
      __syncthreads();
    }
  }

  // ---- epilogue: bias, store y, GN partial sums
  // C/D layout: col(p) = lane&15, row(o) = (lane>>4)*4 + reg
  float psum[2] = {0.f, 0.f}, psq[2] = {0.f, 0.f};
  int orl = (lane >> 4) * 4;
  int pl = lane & 15;
  const size_t ybase = (size_t)bs * CC * HWSZ;
#pragma unroll
  for (int mb = 0; mb < 4; ++mb) {
    int gi = mb >> 1;
#pragma unroll
    for (int r = 0; r < 4; ++r) {
      int o = o0 + wm * 64 + mb * 16 + orl + r;
      float pb = proj_b[o];
      float* yrow = y + ybase + (size_t)o * HWSZ + p0 + wn * 64 + pl;
#pragma unroll
      for (int nb = 0; nb < 4; ++nb) {
        float v = acc[mb][nb][r] + pb;
        yrow[nb * 16] = v;
        psum[gi] += v;
        psq[gi] += v * v;
      }
    }
  }
#pragma unroll
  for (int off = 32; off > 0; off >>= 1) {
#pragma unroll
    for (int k = 0; k < 2; ++k) {
      psum[k] += __shfl_down(psum[k], off, 64);
      psq[k] += __shfl_down(psq[k], off, 64);
    }
  }
  if (lane == 0) {
    int gb = bs * 8 + ot * 4 + wm * 2;
    atomicAdd(&stats[gb], psum[0]);
    atomicAdd(&stats[gb + 1], psum[1]);
    atomicAdd(&stats[128 + gb], psq[0]);
    atomicAdd(&stats[128 + gb + 1], psq[1]);
  }
}

// ---------------------------------------------------------------------------
// K5: GroupNorm affine + exact GELU + residual. In-place on d_out.
// ---------------------------------------------------------------------------
__global__ __launch_bounds__(256) void out_kernel(
    const float* __restrict__ x, const float* __restrict__ stats,
    const float* __restrict__ gamma, const float* __restrict__ beta,
    float* __restrict__ out) {
  int plane = blockIdx.x;
  int b = plane >> 8, c = plane & 255, g = c >> 5;
  const float inv_n = 1.0f / (32.0f * (float)HWSZ);
  float mean = stats[b * 8 + g] * inv_n;
  float var = stats[128 + b * 8 + g] * inv_n - mean * mean;
  float rstd = rsqrtf(var + EPSV);
  float scale = gamma[c] * rstd;
  float shift = beta[c] - mean * scale;

  const size_t base = (size_t)plane * HWSZ;
  for (int i = threadIdx.x; i < HWSZ / 4; i += 256) {
    float4 v = *(const float4*)(out + base + 4 * (size_t)i);
    float4 xv = *(const float4*)(x + base + 4 * (size_t)i);
    float r[4] = {v.x, v.y, v.z, v.w};
    float xr[4] = {xv.x, xv.y, xv.z, xv.w};
#pragma unroll
    for (int k = 0; k < 4; ++k) {
      float t = r[k] * scale + shift;
      float ge = 0.5f * t * (1.0f + erff(t * 0.70710678118654752f));
      r[k] = ge + xr[k];
    }
    *(float4*)(out + base + 4 * (size_t)i) = make_float4(r[0], r[1], r[2], r[3]);
  }
}

// ---------------------------------------------------------------------------
extern "C" void kernel_launch(void* const* d_in, const int* in_sizes, int n_in,
                              void* d_out, int out_size, void* d_ws, size_t ws_size,
                              hipStream_t stream) {
  const float* x      = (const float*)d_in[0];
  const float* fbank  = (const float*)d_in[1];   // [NF,1,7,7]
  const float* sel_w  = (const float*)d_in[2];   // [NF,C]
  const float* sel_b  = (const float*)d_in[3];   // [NF]
  const float* proj_w = (const float*)d_in[4];   // [C,C,1,1]
  const float* proj_b = (const float*)d_in[5];   // [C]
  const float* gamma  = (const float*)d_in[6];   // [C]
  const float* beta   = (const float*)d_in[7];   // [C]
  float* out = (float*)d_out;

  // ws layout: fb bf16 [B*C*HW] | ap bf16 [65536] | pooled f32 | combined f32 | stats f32
  unsigned short* fb = (unsigned short*)d_ws;
  unsigned short* apk = fb + (size_t)BB * CC * HWSZ;
  float* pooled   = (float*)(apk + 65536);
  float* combined = pooled + BB * CC;
  float* stats    = combined + BB * 64;

  hipLaunchKernelGGL(pack_a_kernel, dim3(256), dim3(256), 0, stream, proj_w, apk);
  hipLaunchKernelGGL(pool_kernel, dim3(BB * CC), dim3(256), 0, stream, x, pooled);
  hipLaunchKernelGGL(selector_kernel, dim3(1), dim3(256), 0, stream,
                     pooled, sel_w, sel_b, fbank, combined, stats);
  hipLaunchKernelGGL(dwconv_kernel, dim3(BB * CC, HH / TR), dim3(256), 0, stream,
                     x, combined, fb);
  hipLaunchKernelGGL(gemm_kernel, dim3(BB * 256), dim3(256), 0, stream,
                     fb, apk, proj_b, out, stats);
  hipLaunchKernelGGL(out_kernel, dim3(BB * CC), dim3(256), 0, stream,
                     x, stats, gamma, beta, out);
}

// Round 4
// 579.473 us; speedup vs baseline: 1.6306x; 1.0340x over previous
//
#include <hip/hip_runtime.h>
#include <math.h>

// Problem constants
#define BB 16
#define CC 256
#define HH 128
#define WW 128
#define HWSZ 16384        // H*W
#define NF 8
#define EPSV 1e-5f

typedef __attribute__((ext_vector_type(8))) short short8;   // 8 bf16 = 4 VGPRs
typedef __attribute__((ext_vector_type(4))) float f32x4;

static __device__ __forceinline__ unsigned short f2bf(float f) {
  unsigned int u = __float_as_uint(f);
  u += 0x7fffu + ((u >> 16) & 1u);       // round-to-nearest-even
  return (unsigned short)(u >> 16);
}

static __device__ __forceinline__ float bf2f(unsigned int h) {
  return __uint_as_float(h << 16);
}

// ---------------------------------------------------------------------------
// K0: pack proj_w [o][c] fp32 -> bf16 in MFMA A-fragment order:
//     ap[((MB*8+kb)*64+lane)*8+e] = w[MB*16+(lane&15)][kb*32+(lane>>4)*8+e]
// ---------------------------------------------------------------------------
__global__ __launch_bounds__(256) void pack_a_kernel(
    const float* __restrict__ pw, unsigned short* __restrict__ ap) {
  int idx = blockIdx.x * 256 + threadIdx.x;     // 0..65535
  int e = idx & 7;
  int lane = (idx >> 3) & 63;
  int kb = (idx >> 9) & 7;
  int mb = idx >> 12;
  int o = mb * 16 + (lane & 15);
  int c = kb * 32 + (lane >> 4) * 8 + e;
  ap[idx] = f2bf(pw[o * 256 + c]);
}

// ---------------------------------------------------------------------------
// K1: pooled[b,c] = mean over HW.  One block per (b,c) plane.
// ---------------------------------------------------------------------------
__global__ __launch_bounds__(256) void pool_kernel(
    const float* __restrict__ x, float* __restrict__ pooled) {
  int plane = blockIdx.x;
  const float4* xp = (const float4*)(x + (size_t)plane * HWSZ);
  int tid = threadIdx.x;
  float s = 0.f;
#pragma unroll
  for (int i = 0; i < 16; ++i) {
    float4 v = xp[tid + i * 256];
    s += v.x + v.y + v.z + v.w;
  }
#pragma unroll
  for (int off = 32; off > 0; off >>= 1) s += __shfl_down(s, off, 64);
  __shared__ float ls[4];
  if ((tid & 63) == 0) ls[tid >> 6] = s;
  __syncthreads();
  if (tid == 0) pooled[plane] = (ls[0] + ls[1] + ls[2] + ls[3]) * (1.0f / 16384.0f);
}

// ---------------------------------------------------------------------------
// K2: selector: GAP -> linear -> softmax -> mix filter bank; zero GN stats.
// ---------------------------------------------------------------------------
__global__ __launch_bounds__(256) void selector_kernel(
    const float* __restrict__ pooled, const float* __restrict__ sel_w,
    const float* __restrict__ sel_b, const float* __restrict__ fbank,
    float* __restrict__ combined, float* __restrict__ stats) {
  int tid = threadIdx.x;
  stats[tid] = 0.f;  // 256 slots: [0..127] sum, [128..255] sumsq
  __shared__ float lg[BB][NF];
  __shared__ float wsm[BB][NF];
  if (tid < BB * NF) {
    int b = tid >> 3, n = tid & 7;
    const float* p = pooled + b * CC;
    const float* w = sel_w + n * CC;
    float d = sel_b[n];
    for (int c = 0; c < CC; c += 4) {
      d += p[c] * w[c] + p[c + 1] * w[c + 1] + p[c + 2] * w[c + 2] + p[c + 3] * w[c + 3];
    }
    lg[b][n] = d;
  }
  __syncthreads();
  if (tid < BB) {
    int b = tid;
    float m = lg[b][0];
#pragma unroll
    for (int n = 1; n < NF; ++n) m = fmaxf(m, lg[b][n]);
    float e[NF];
    float s = 0.f;
#pragma unroll
    for (int n = 0; n < NF; ++n) { e[n] = expf(lg[b][n] - m); s += e[n]; }
    float inv = 1.0f / s;
#pragma unroll
    for (int n = 0; n < NF; ++n) wsm[b][n] = e[n] * inv;
  }
  __syncthreads();
  for (int i = tid; i < BB * 49; i += 256) {
    int b = i / 49, j = i % 49;
    float acc = 0.f;
#pragma unroll
    for (int n = 0; n < NF; ++n) acc += wsm[b][n] * fbank[n * 49 + j];
    combined[b * 64 + j] = acc;
  }
}

// ---------------------------------------------------------------------------
// K3: depthwise 7x7 conv, per-sample filter; fp32 compute, bf16 output.
// ---------------------------------------------------------------------------
#define TR 32
__global__ __launch_bounds__(256) void dwconv_kernel(
    const float* __restrict__ x, const float* __restrict__ combined,
    unsigned short* __restrict__ fbp) {
  int plane = blockIdx.x;          // b*256 + c
  int rt = blockIdx.y;             // 0..3
  int b = plane >> 8;
  int r0 = rt * TR;
  int tid = threadIdx.x;

  __shared__ float xs[TR + 6][136];

  float kf[49];
  {
    const float* cb = combined + b * 64;
#pragma unroll
    for (int i = 0; i < 49; ++i) kf[i] = cb[i];
  }

  const size_t pbase = (size_t)plane * HWSZ;
  for (int idx = tid; idx < (TR + 6) * 34; idx += 256) {
    int row = idx / 34;
    int seg = idx % 34;
    int r = r0 - 3 + row;
    int c = seg * 4 - 4;
    float4 v = make_float4(0.f, 0.f, 0.f, 0.f);
    if (r >= 0 && r < HH && c >= 0 && c < WW) {
      v = *(const float4*)(x + pbase + (size_t)r * WW + c);
    }
    *(float4*)&xs[row][seg * 4] = v;
  }
  __syncthreads();

  int cg = tid & 31;
  int rg = tid >> 5;
  float acc[4][4] = {};

#pragma unroll
  for (int ri = 0; ri < 10; ++ri) {
    int lrow = 4 * rg + ri;
    float xr[12];
#pragma unroll
    for (int s = 0; s < 3; ++s)
      *(float4*)&xr[4 * s] = *(const float4*)&xs[lrow][cg * 4 + 4 * s];
#pragma unroll
    for (int orr = 0; orr < 4; ++orr) {
      int dy = ri - orr;
      if (dy < 0 || dy > 6) continue;
#pragma unroll
      for (int oc = 0; oc < 4; ++oc) {
#pragma unroll
        for (int dx = 0; dx < 7; ++dx) {
          acc[orr][oc] += xr[oc + dx + 1] * kf[dy * 7 + dx];
        }
      }
    }
  }

#pragma unroll
  for (int orr = 0; orr < 4; ++orr) {
    ushort4 sv;
    sv.x = f2bf(acc[orr][0]);
    sv.y = f2bf(acc[orr][1]);
    sv.z = f2bf(acc[orr][2]);
    sv.w = f2bf(acc[orr][3]);
    *(ushort4*)(fbp + pbase + (size_t)(r0 + 4 * rg + orr) * WW + 4 * cg) = sv;
  }
}

// ---------------------------------------------------------------------------
// K4: 1x1 conv as bf16 MFMA GEMM: y[b,o,p] = sum_c W[o][c]*F[b][c][p] + pb[o]
//     Block = 256 o x 64 p; 4 waves, each 64 o x 64 p (4x4 16x16x32 MFMA).
//     B tile [32c][64p] reg-staged to LDS transposed [p][c] with XOR swizzle
//     (round-2-proven mapping), double-buffered; next-tile loads issued
//     before MFMAs (T14), pack+write after, one __syncthreads per K-step.
//     Output y in bf16; epilogue accumulates GN partial sums (fp32).
// ---------------------------------------------------------------------------
#define SWZ(p) ((((p) >> 1) ^ ((p) >> 4)) & 3)

__global__ __launch_bounds__(256, 2) void gemm_kernel(
    const unsigned short* __restrict__ fb, const unsigned short* __restrict__ ap,
    const float* __restrict__ proj_b, unsigned short* __restrict__ yb,
    float* __restrict__ stats) {
  int bid = blockIdx.x;
  int bs = bid >> 8;               // sample
  int pt = bid & 255;              // pixel tile (64 wide)
  int p0 = pt * 64;
  int tid = threadIdx.x;
  int lane = tid & 63;
  int wave = tid >> 6;             // 0..3 -> o rows wave*64..+63

  __shared__ unsigned short Bs[2][64][32];   // [buf][p][c-swizzled], 8 KB

  // staging: thread -> c rows {2*cpair, 2*cpair+1}, p = 4*pquad..+3
  int cpair = tid >> 4;            // 0..15
  int pquad = tid & 15;            // 0..15
  const unsigned short* srcA =
      fb + (size_t)bs * CC * HWSZ + (size_t)(2 * cpair) * HWSZ + p0 + 4 * pquad;

  // A fragment base (packed, L2-resident): MB = wave*4 + mb
  const unsigned short* apl = ap + (size_t)(wave * 4) * 4096 + lane * 8;

  f32x4 acc[4][4];
#pragma unroll
  for (int mb = 0; mb < 4; ++mb)
#pragma unroll
    for (int nb = 0; nb < 4; ++nb) acc[mb][nb] = (f32x4){0.f, 0.f, 0.f, 0.f};

  short8 af[4], afn[4];
#pragma unroll
  for (int mb = 0; mb < 4; ++mb) af[mb] = *(const short8*)(apl + mb * 4096);

  // ---- prologue: stage tile 0 into buf 0
  {
    uint2 va = *(const uint2*)srcA;
    uint2 vb = *(const uint2*)(srcA + HWSZ);
    unsigned int wa[2] = {va.x, va.y}, wb[2] = {vb.x, vb.y};
#pragma unroll
    for (int j = 0; j < 4; ++j) {
      int p = 4 * pquad + j;
      int cc = (2 * cpair) ^ (SWZ(p) << 3);
      unsigned int lo = (wa[j >> 1] >> ((j & 1) * 16)) & 0xffffu;
      unsigned int hi = (wb[j >> 1] >> ((j & 1) * 16)) & 0xffffu;
      *(unsigned int*)&Bs[0][p][cc] = lo | (hi << 16);
    }
  }
  __syncthreads();

#pragma unroll
  for (int kb = 0; kb < 8; ++kb) {
    const int cur = kb & 1;
    uint2 va2, vb2;
    if (kb < 7) {                  // T14: issue next-tile loads early
      const unsigned short* s = srcA + (size_t)(kb + 1) * 32 * HWSZ;
      va2 = *(const uint2*)s;
      vb2 = *(const uint2*)(s + HWSZ);
#pragma unroll
      for (int mb = 0; mb < 4; ++mb)
        afn[mb] = *(const short8*)(apl + mb * 4096 + (kb + 1) * 512);
    }
    // B fragments from LDS (round-2-proven swizzled read)
    short8 bfr[4];
#pragma unroll
    for (int nb = 0; nb < 4; ++nb) {
      int pp = nb * 16 + (lane & 15);
      int cc0 = ((lane >> 4) * 8) ^ (SWZ(pp) << 3);
      bfr[nb] = *(const short8*)&Bs[cur][pp][cc0];
    }
#pragma unroll
    for (int mb = 0; mb < 4; ++mb)
#pragma unroll
      for (int nb = 0; nb < 4; ++nb)
        acc[mb][nb] = __builtin_amdgcn_mfma_f32_16x16x32_bf16(
            af[mb], bfr[nb], acc[mb][nb], 0, 0, 0);
    if (kb < 7) {                  // pack + write next tile, then barrier
      unsigned int wa[2] = {va2.x, va2.y}, wb[2] = {vb2.x, vb2.y};
#pragma unroll
      for (int j = 0; j < 4; ++j) {
        int p = 4 * pquad + j;
        int cc = (2 * cpair) ^ (SWZ(p) << 3);
        unsigned int lo = (wa[j >> 1] >> ((j & 1) * 16)) & 0xffffu;
        unsigned int hi = (wb[j >> 1] >> ((j & 1) * 16)) & 0xffffu;
        *(unsigned int*)&Bs[cur ^ 1][p][cc] = lo | (hi << 16);
      }
#pragma unroll
      for (int mb = 0; mb < 4; ++mb) af[mb] = afn[mb];
      __syncthreads();
    }
  }

  // ---- epilogue: bias, store y (bf16), GN partial sums (fp32)
  // C/D layout: col(p) = lane&15, row(o) = (lane>>4)*4 + reg
  float psum[2] = {0.f, 0.f}, psq[2] = {0.f, 0.f};
  int orl = (lane >> 4) * 4;
  int pl = lane & 15;
  const size_t ybase = (size_t)bs * CC * HWSZ;
#pragma unroll
  for (int mb = 0; mb < 4; ++mb) {
    int gi = mb >> 1;
#pragma unroll
    for (int r = 0; r < 4; ++r) {
      int o = wave * 64 + mb * 16 + orl + r;
      float pb = proj_b[o];
      unsigned short* yrow = yb + ybase + (size_t)o * HWSZ + p0 + pl;
#pragma unroll
      for (int nb = 0; nb < 4; ++nb) {
        float v = acc[mb][nb][r] + pb;
        yrow[nb * 16] = f2bf(v);
        psum[gi] += v;
        psq[gi] += v * v;
      }
    }
  }
#pragma unroll
  for (int off = 32; off > 0; off >>= 1) {
#pragma unroll
    for (int k = 0; k < 2; ++k) {
      psum[k] += __shfl_down(psum[k], off, 64);
      psq[k] += __shfl_down(psq[k], off, 64);
    }
  }
  if (lane == 0) {
    int gb = bs * 8 + wave * 2;    // wave covers 2 GN groups (64 ch)
    atomicAdd(&stats[gb], psum[0]);
    atomicAdd(&stats[gb + 1], psum[1]);
    atomicAdd(&stats[128 + gb], psq[0]);
    atomicAdd(&stats[128 + gb + 1], psq[1]);
  }
}

// ---------------------------------------------------------------------------
// K5: GroupNorm affine + exact GELU + residual. Reads bf16 y, writes fp32 out.
// ---------------------------------------------------------------------------
__global__ __launch_bounds__(256) void out_kernel(
    const float* __restrict__ x, const unsigned short* __restrict__ yb,
    const float* __restrict__ stats, const float* __restrict__ gamma,
    const float* __restrict__ beta, float* __restrict__ out) {
  int plane = blockIdx.x;
  int b = plane >> 8, c = plane & 255, g = c >> 5;
  const float inv_n = 1.0f / (32.0f * (float)HWSZ);
  float mean = stats[b * 8 + g] * inv_n;
  float var = stats[128 + b * 8 + g] * inv_n - mean * mean;
  float rstd = rsqrtf(var + EPSV);
  float scale = gamma[c] * rstd;
  float shift = beta[c] - mean * scale;

  const size_t base = (size_t)plane * HWSZ;
  for (int i = threadIdx.x; i < HWSZ / 8; i += 256) {
    uint4 yv = *(const uint4*)(yb + base + 8 * (size_t)i);
    float4 x0 = *(const float4*)(x + base + 8 * (size_t)i);
    float4 x1 = *(const float4*)(x + base + 8 * (size_t)i + 4);
    unsigned int yw[4] = {yv.x, yv.y, yv.z, yv.w};
    float r[8];
    float xr[8] = {x0.x, x0.y, x0.z, x0.w, x1.x, x1.y, x1.z, x1.w};
#pragma unroll
    for (int k = 0; k < 8; ++k) {
      unsigned int h = (yw[k >> 1] >> ((k & 1) * 16)) & 0xffffu;
      float t = bf2f(h) * scale + shift;
      float ge = 0.5f * t * (1.0f + erff(t * 0.70710678118654752f));
      r[k] = ge + xr[k];
    }
    *(float4*)(out + base + 8 * (size_t)i) = make_float4(r[0], r[1], r[2], r[3]);
    *(float4*)(out + base + 8 * (size_t)i + 4) = make_float4(r[4], r[5], r[6], r[7]);
  }
}

// ---------------------------------------------------------------------------
extern "C" void kernel_launch(void* const* d_in, const int* in_sizes, int n_in,
                              void* d_out, int out_size, void* d_ws, size_t ws_size,
                              hipStream_t stream) {
  const float* x      = (const float*)d_in[0];
  const float* fbank  = (const float*)d_in[1];   // [NF,1,7,7]
  const float* sel_w  = (const float*)d_in[2];   // [NF,C]
  const float* sel_b  = (const float*)d_in[3];   // [NF]
  const float* proj_w = (const float*)d_in[4];   // [C,C,1,1]
  const float* proj_b = (const float*)d_in[5];   // [C]
  const float* gamma  = (const float*)d_in[6];   // [C]
  const float* beta   = (const float*)d_in[7];   // [C]
  float* out = (float*)d_out;

  // ws layout: fb bf16 [B*C*HW] | yb bf16 [B*C*HW] | ap bf16 [65536] | f32 small
  unsigned short* fb = (unsigned short*)d_ws;
  unsigned short* yb = fb + (size_t)BB * CC * HWSZ;
  unsigned short* apk = yb + (size_t)BB * CC * HWSZ;
  float* pooled   = (float*)(apk + 65536);
  float* combined = pooled + BB * CC;
  float* stats    = combined + BB * 64;

  hipLaunchKernelGGL(pack_a_kernel, dim3(256), dim3(256), 0, stream, proj_w, apk);
  hipLaunchKernelGGL(pool_kernel, dim3(BB * CC), dim3(256), 0, stream, x, pooled);
  hipLaunchKernelGGL(selector_kernel, dim3(1), dim3(256), 0, stream,
                     pooled, sel_w, sel_b, fbank, combined, stats);
  hipLaunchKernelGGL(dwconv_kernel, dim3(BB * CC, HH / TR), dim3(256), 0, stream,
                     x, combined, fb);
  hipLaunchKernelGGL(gemm_kernel, dim3(BB * 256), dim3(256), 0, stream,
                     fb, apk, proj_b, yb, stats);
  hipLaunchKernelGGL(out_kernel, dim3(BB * CC), dim3(256), 0, stream,
                     x, yb, stats, gamma, beta, out);
}